// Round 1
// baseline (325.674 us; speedup 1.0000x reference)
//
#include <hip/hip_runtime.h>
#include <cstdint>
#include <cstddef>

#define B_ROWS 16384
#define DIMSZ  1024
#define NH     8
#define HD     128

typedef __attribute__((ext_vector_type(8))) __bf16 bf16x8;
typedef __attribute__((ext_vector_type(4))) float f32x4;
typedef __attribute__((ext_vector_type(8))) unsigned short ushort8v;

__device__ __forceinline__ unsigned short f2bf(float f) {
  union { float f; unsigned int u; } x; x.f = f;
  unsigned int r = x.u + 0x7FFFu + ((x.u >> 16) & 1u);   // RNE
  return (unsigned short)(r >> 16);
}
__device__ __forceinline__ float bf2f(unsigned short h) {
  union { unsigned int u; float f; } x; x.u = ((unsigned int)h) << 16;
  return x.f;
}

// async global->LDS, 16B per lane, wave-uniform LDS base (guide §5)
__device__ __forceinline__ void gload_lds16(const void* g, void* l) {
  __builtin_amdgcn_global_load_lds(
      (__attribute__((address_space(1))) void*)(uintptr_t)g,
      (__attribute__((address_space(3))) void*)(uintptr_t)l, 16, 0, 0);
}

// ---------------- fp32 -> bf16 convert (vectorized, 8 elems/thread) ----------
__global__ __launch_bounds__(256) void cvt_f32_bf16_k(const float* __restrict__ in,
                                                      unsigned short* __restrict__ out,
                                                      int n8) {
  int i = blockIdx.x * 256 + threadIdx.x;
  if (i >= n8) return;
  const float4* p = (const float4*)in + 2 * (size_t)i;
  float4 a = p[0], b = p[1];
  ushort8v o;
  o[0] = f2bf(a.x); o[1] = f2bf(a.y); o[2] = f2bf(a.z); o[3] = f2bf(a.w);
  o[4] = f2bf(b.x); o[5] = f2bf(b.y); o[6] = f2bf(b.z); o[7] = f2bf(b.w);
  *(ushort8v*)(out + 8 * (size_t)i) = o;
}

// ---------------- W[k][n] fp32 -> Wt[n][k] bf16 (tiled transpose) ------------
__global__ __launch_bounds__(256) void transpose_cvt_k(const float* __restrict__ W,
                                                       unsigned short* __restrict__ Wt,
                                                       int R, int C) {
  __shared__ float tile[32][33];
  int bx = blockIdx.x * 32, by = blockIdx.y * 32;
  int tx = threadIdx.x & 31, ty = threadIdx.x >> 5;
  #pragma unroll
  for (int j = ty; j < 32; j += 8)
    tile[j][tx] = W[(size_t)(by + j) * C + bx + tx];
  __syncthreads();
  #pragma unroll
  for (int j = ty; j < 32; j += 8)
    Wt[(size_t)(bx + j) * R + by + tx] = f2bf(tile[tx][j]);
}

// ---------------- bf16 MFMA GEMM: C[M,N] = A[M,K] @ Bt[N,K]^T + bias ---------
// m97 structure: 128x128 tile, BK=32, 4 waves (2x2), 4x4 16x16x32 frags/wave.
template <int OUT_BF16>
__global__ __launch_bounds__(256) void gemm_k(const unsigned short* __restrict__ A,
                                              const unsigned short* __restrict__ Bt,
                                              const float* __restrict__ bias,
                                              void* __restrict__ Cout,
                                              int M, int N, int K) {
  __shared__ __align__(16) unsigned short As[128 * 32];
  __shared__ __align__(16) unsigned short Bs[128 * 32];
  const int tid = threadIdx.x, wid = tid >> 6, lane = tid & 63;
  const int brow = blockIdx.y << 7, bcol = blockIdx.x << 7;
  const int wr = wid >> 1, wc = wid & 1;
  const int kg = lane >> 4, lr = lane & 15;
  f32x4 acc[4][4] = {};
  const unsigned short* Ab = A + (size_t)brow * K;
  const unsigned short* Bb = Bt + (size_t)bcol * K;

  for (int k0 = 0; k0 < K; k0 += 32) {
    // stage A,B tiles (128x32 bf16 = 8KB each): 2 gload_lds16 per operand/thread
    #pragma unroll
    for (int i = 0; i < 2; ++i) {
      int e = ((i * 4 + wid) * 64 + lane) * 8;   // flat bf16 index in tile
      int r = e >> 5, c = e & 31;
      gload_lds16(Ab + (size_t)r * K + k0 + c, (char*)As + (i * 4 + wid) * 1024);
      gload_lds16(Bb + (size_t)r * K + k0 + c, (char*)Bs + (i * 4 + wid) * 1024);
    }
    __syncthreads();   // drains vmcnt for global_load_lds

    bf16x8 af[4], bfr[4];
    #pragma unroll
    for (int m = 0; m < 4; ++m)
      af[m] = *(const bf16x8*)&As[(wr * 64 + m * 16 + lr) * 32 + kg * 8];
    #pragma unroll
    for (int n = 0; n < 4; ++n)
      bfr[n] = *(const bf16x8*)&Bs[(wc * 64 + n * 16 + lr) * 32 + kg * 8];
    #pragma unroll
    for (int m = 0; m < 4; ++m)
      #pragma unroll
      for (int n = 0; n < 4; ++n)
        acc[m][n] = __builtin_amdgcn_mfma_f32_16x16x32_bf16(af[m], bfr[n], acc[m][n], 0, 0, 0);
    __syncthreads();
  }

  // epilogue: D col=lane&15, row=(lane>>4)*4+reg (m89-verified)
  const int row0 = brow + wr * 64, col0 = bcol + wc * 64;
  const int cg4 = (lane >> 4) * 4;
  #pragma unroll
  for (int n = 0; n < 4; ++n) {
    int col = col0 + n * 16 + lr;
    float bv = bias[col];
    #pragma unroll
    for (int m = 0; m < 4; ++m) {
      #pragma unroll
      for (int r = 0; r < 4; ++r) {
        int row = row0 + m * 16 + cg4 + r;
        float v = acc[m][n][r] + bv;
        if (OUT_BF16)
          ((unsigned short*)Cout)[(size_t)row * N + col] = f2bf(v);
        else
          ((float*)Cout)[(size_t)row * N + col] = v;
      }
    }
  }
}

// ---------------- per-sample 8x8 cross-head attention ------------------------
// one wave per sample; Q,K,V rows (8x128 bf16) staged in LDS, stride padded to
// 136 elems so the 8 distinct K-rows land on distinct bank groups.
__global__ __launch_bounds__(256) void attn_k(const unsigned short* __restrict__ Q,
                                              const unsigned short* __restrict__ Kc,
                                              const unsigned short* __restrict__ V,
                                              unsigned short* __restrict__ ctx) {
  __shared__ __align__(16) unsigned short sm[4][3][NH][136];
  const int wid = threadIdx.x >> 6, lane = threadIdx.x & 63;
  const int b = (blockIdx.x << 2) + wid;

  const unsigned short* bases[3] = { Q + (size_t)b * DIMSZ,
                                     Kc + (size_t)b * DIMSZ,
                                     V + (size_t)b * DIMSZ };
  const int row = lane >> 3, ch = lane & 7;   // 8 rows x 8 chunks of 16 elems
  #pragma unroll
  for (int m = 0; m < 3; ++m) {
    ushort8v v0 = *(const ushort8v*)(bases[m] + row * HD + ch * 16);
    ushort8v v1 = *(const ushort8v*)(bases[m] + row * HD + ch * 16 + 8);
    *(ushort8v*)&sm[wid][m][row][ch * 16] = v0;
    *(ushort8v*)&sm[wid][m][row][ch * 16 + 8] = v1;
  }
  __syncthreads();

  // lane (h,g) = (lane>>3, lane&7): score = Q[h,:].K[g,:] / sqrt(128)
  const int h = lane >> 3, g = lane & 7;
  const unsigned short* qr = &sm[wid][0][h][0];
  const unsigned short* kr = &sm[wid][1][g][0];
  float s = 0.f;
  #pragma unroll
  for (int c = 0; c < 16; ++c) {
    ushort8v qv = *(const ushort8v*)(qr + c * 8);
    ushort8v kv = *(const ushort8v*)(kr + c * 8);
    #pragma unroll
    for (int j = 0; j < 8; ++j) s += bf2f(qv[j]) * bf2f(kv[j]);
  }
  s *= 0.088388347648318447f;   // 1/sqrt(128)

  // softmax across g within each 8-lane group
  float mx = s;
  #pragma unroll
  for (int o = 1; o < 8; o <<= 1) mx = fmaxf(mx, __shfl_xor(mx, o));
  float e = __expf(s - mx);
  float sum = e;
  #pragma unroll
  for (int o = 1; o < 8; o <<= 1) sum += __shfl_xor(sum, o);
  float attn = e / sum;

  // context: lane owns h2 = lane>>3, d = d0..d0+15 (d0 = (lane&7)*16)
  const int h2 = lane >> 3, d0 = (lane & 7) * 16;
  float cacc[16];
  #pragma unroll
  for (int j = 0; j < 16; ++j) cacc[j] = 0.f;
  #pragma unroll
  for (int g2 = 0; g2 < 8; ++g2) {
    float a = __shfl(attn, (lane & 56) + g2);   // attn[h2][g2] lives in lane h2*8+g2
    const unsigned short* vr = &sm[wid][2][g2][d0];
    ushort8v v0 = *(const ushort8v*)vr;
    ushort8v v1 = *(const ushort8v*)(vr + 8);
    #pragma unroll
    for (int j = 0; j < 8; ++j) {
      cacc[j]     += a * bf2f(v0[j]);
      cacc[8 + j] += a * bf2f(v1[j]);
    }
  }
  ushort8v o0, o1;
  #pragma unroll
  for (int j = 0; j < 8; ++j) { o0[j] = f2bf(cacc[j]); o1[j] = f2bf(cacc[8 + j]); }
  unsigned short* op = ctx + (size_t)b * DIMSZ + h2 * HD + d0;
  *(ushort8v*)op = o0;
  *(ushort8v*)(op + 8) = o1;
}

// ---------------- launcher ---------------------------------------------------
extern "C" void kernel_launch(void* const* d_in, const int* in_sizes, int n_in,
                              void* d_out, int out_size, void* d_ws, size_t ws_size,
                              hipStream_t stream) {
  const float* feat1 = (const float*)d_in[0];
  const float* feat2 = (const float*)d_in[1];
  const float* Wq = (const float*)d_in[2];
  const float* bq = (const float*)d_in[3];
  const float* Wk = (const float*)d_in[4];
  const float* bk = (const float*)d_in[5];
  const float* Wv = (const float*)d_in[6];
  const float* bv = (const float*)d_in[7];
  const float* Wo = (const float*)d_in[8];
  const float* bo = (const float*)d_in[9];
  float* out = (float*)d_out;

  const int M = B_ROWS, N = DIMSZ, K = DIMSZ;
  char* ws = (char*)d_ws;
  const size_t featB = (size_t)M * DIMSZ * 2;   // 32 MB per bf16 feature buffer
  const size_t wB = (size_t)DIMSZ * DIMSZ * 2;  // 2 MB per bf16 weight
  unsigned short* f1b = (unsigned short*)(ws);              // feat1 bf16 (later reused as ctx)
  unsigned short* f2b = (unsigned short*)(ws + featB);
  unsigned short* Qb  = (unsigned short*)(ws + 2 * featB);
  unsigned short* Kb  = (unsigned short*)(ws + 3 * featB);
  unsigned short* Vb  = (unsigned short*)(ws + 4 * featB);
  unsigned short* Wqt = (unsigned short*)(ws + 5 * featB);
  unsigned short* Wkt = (unsigned short*)(ws + 5 * featB + wB);
  unsigned short* Wvt = (unsigned short*)(ws + 5 * featB + 2 * wB);
  unsigned short* Wot = (unsigned short*)(ws + 5 * featB + 3 * wB);
  unsigned short* ctx = f1b;   // feat1_bf is dead after the Q GEMM

  const int n8 = M * DIMSZ / 8;
  cvt_f32_bf16_k<<<(n8 + 255) / 256, 256, 0, stream>>>(feat1, f1b, n8);
  cvt_f32_bf16_k<<<(n8 + 255) / 256, 256, 0, stream>>>(feat2, f2b, n8);

  dim3 tg(DIMSZ / 32, DIMSZ / 32);
  transpose_cvt_k<<<tg, 256, 0, stream>>>(Wq, Wqt, DIMSZ, DIMSZ);
  transpose_cvt_k<<<tg, 256, 0, stream>>>(Wk, Wkt, DIMSZ, DIMSZ);
  transpose_cvt_k<<<tg, 256, 0, stream>>>(Wv, Wvt, DIMSZ, DIMSZ);
  transpose_cvt_k<<<tg, 256, 0, stream>>>(Wo, Wot, DIMSZ, DIMSZ);

  dim3 gg(N / 128, M / 128);
  gemm_k<1><<<gg, 256, 0, stream>>>(f1b, Wqt, bq, Qb, M, N, K);
  gemm_k<1><<<gg, 256, 0, stream>>>(f2b, Wkt, bk, Kb, M, N, K);
  gemm_k<1><<<gg, 256, 0, stream>>>(f2b, Wvt, bv, Vb, M, N, K);

  attn_k<<<M / 4, 256, 0, stream>>>(Qb, Kb, Vb, ctx);

  gemm_k<0><<<gg, 256, 0, stream>>>(ctx, Wot, bo, out, M, N, K);
}

// Round 2
// 246.392 us; speedup vs baseline: 1.3218x; 1.3218x over previous
//
#include <hip/hip_runtime.h>
#include <cstdint>
#include <cstddef>

#define B_ROWS 16384
#define DIMSZ  1024
#define NH     8
#define HD     128
#define KDIM   1024

typedef __attribute__((ext_vector_type(8))) __bf16 bf16x8;
typedef __attribute__((ext_vector_type(4))) float f32x4;
typedef __attribute__((ext_vector_type(8))) unsigned short ushort8v;

__device__ __forceinline__ unsigned short f2bf(float f) {
  union { float f; unsigned int u; } x; x.f = f;
  unsigned int r = x.u + 0x7FFFu + ((x.u >> 16) & 1u);   // RNE
  return (unsigned short)(r >> 16);
}
__device__ __forceinline__ float bf2f(unsigned short h) {
  union { unsigned int u; float f; } x; x.u = ((unsigned int)h) << 16;
  return x.f;
}

__device__ __forceinline__ void gload_lds16(const void* g, void* l) {
  __builtin_amdgcn_global_load_lds(
      (__attribute__((address_space(1))) void*)(uintptr_t)g,
      (__attribute__((address_space(3))) void*)(uintptr_t)l, 16, 0, 0);
}

// ---------------- fp32 -> bf16 convert ---------------------------------------
__global__ __launch_bounds__(256) void cvt_f32_bf16_k(const float* __restrict__ in,
                                                      unsigned short* __restrict__ out,
                                                      int n8) {
  int i = blockIdx.x * 256 + threadIdx.x;
  if (i >= n8) return;
  const float4* p = (const float4*)in + 2 * (size_t)i;
  float4 a = p[0], b = p[1];
  ushort8v o;
  o[0] = f2bf(a.x); o[1] = f2bf(a.y); o[2] = f2bf(a.z); o[3] = f2bf(a.w);
  o[4] = f2bf(b.x); o[5] = f2bf(b.y); o[6] = f2bf(b.z); o[7] = f2bf(b.w);
  *(ushort8v*)(out + 8 * (size_t)i) = o;
}

// ---------------- W[k][n] fp32 -> Wt[n][k] bf16 ------------------------------
__global__ __launch_bounds__(256) void transpose_cvt_k(const float* __restrict__ W,
                                                       unsigned short* __restrict__ Wt,
                                                       int R, int C) {
  __shared__ float tile[32][33];
  int bx = blockIdx.x * 32, by = blockIdx.y * 32;
  int tx = threadIdx.x & 31, ty = threadIdx.x >> 5;
  #pragma unroll
  for (int j = ty; j < 32; j += 8)
    tile[j][tx] = W[(size_t)(by + j) * C + bx + tx];
  __syncthreads();
  #pragma unroll
  for (int j = ty; j < 32; j += 8)
    Wt[(size_t)(bx + j) * R + by + tx] = f2bf(tile[tx][j]);
}

// ---------------- pipelined bf16 MFMA GEMM -----------------------------------
// C[M,NCOLS] = A[M,K] @ Bt[NCOLS,K]^T + bias.  Tile 256x128, BK=64, 8 waves
// (2x4), 3-deep LDS pipeline (stage tile t+2 during tile t), counted vmcnt(6),
// XOR-swizzled LDS (T2: byte ^= (row&7)<<4 on [*][64] bf16 rows), setprio (T5),
// XCD-aware block swizzle (T1).  Split epilogue at col 1024 for fused KV GEMM.
template <int NCOLS, int OUT_BF16>
__global__ __launch_bounds__(512, 2) void gemm2_k(
    const unsigned short* __restrict__ A,
    const unsigned short* __restrict__ Bt,
    const float* __restrict__ bias0, const float* __restrict__ bias1,
    void* __restrict__ out0, void* __restrict__ out1) {
  constexpr int NBC = NCOLS / 128;
  constexpr int NWG = (B_ROWS / 256) * NBC;
  constexpr int NKT = KDIM / 64;   // 16

  // LDS: A bufs 3 x [256][64] bf16 (16384 elems), B bufs 3 x [128][64] (8192)
  __shared__ __align__(16) unsigned short lds[3 * 16384 + 3 * 8192];  // 144 KiB

  const int tid = threadIdx.x;
  const int wid = tid >> 6, lane = tid & 63;
  const int lr = lane & 15, kg = lane >> 4;
  const int wr = wid >> 2, wc = wid & 3;
  const int swz = (lr & 7) << 4;

  // T1: XCD-aware block swizzle (NWG % 8 == 0 for both instantiations)
  const int x = ((int)blockIdx.x % 8) * (NWG / 8) + (int)blockIdx.x / 8;
  const int bcol = (x % NBC) * 128;
  const int brow = (x / NBC) * 256;

  const char* Ab = (const char*)(A + (size_t)brow * KDIM);
  const char* Bb = (const char*)(Bt + (size_t)bcol * KDIM);
  unsigned short* As0 = lds;
  unsigned short* Bs0 = lds + 3 * 16384;

  // stage one K-tile's A half: linear LDS dest, inverse-swizzled global source
  auto stageA = [&](int t, int buf) {
    char* dstb = (char*)(As0 + buf * 16384);
    #pragma unroll
    for (int r = 0; r < 4; ++r) {
      int g = ((r * 8 + wid) << 6) + lane;
      int row = g >> 3, j = g & 7;
      const char* src = Ab + (size_t)row * (KDIM * 2) + t * 128 + ((j ^ (row & 7)) << 4);
      gload_lds16(src, dstb + ((r * 8 + wid) << 10));
    }
  };
  auto stageB = [&](int t, int buf) {
    char* dstb = (char*)(Bs0 + buf * 8192);
    #pragma unroll
    for (int r = 0; r < 2; ++r) {
      int g = ((r * 8 + wid) << 6) + lane;
      int row = g >> 3, j = g & 7;
      const char* src = Bb + (size_t)row * (KDIM * 2) + t * 128 + ((j ^ (row & 7)) << 4);
      gload_lds16(src, dstb + ((r * 8 + wid) << 10));
    }
  };

  f32x4 acc[8][2] = {};

  // prologue: tiles 0,1 in flight; wait tile0 (leave tile1's 6 loads pending)
  stageA(0, 0); stageB(0, 0);
  stageA(1, 1); stageB(1, 1);
  asm volatile("s_waitcnt vmcnt(6)" ::: "memory");
  __builtin_amdgcn_s_barrier();

  int cb = 0;
  #pragma unroll 1
  for (int t = 0; t < NKT; ++t) {
    const char* AsT = (const char*)(As0 + cb * 16384);
    const char* BsT = (const char*)(Bs0 + cb * 8192);
    int sb = cb + 2; if (sb >= 3) sb -= 3;

    // ---- phase 0: stage A(t+2), compute rows 0-63 of wave tile ----
    if (t + 2 < NKT) stageA(t + 2, sb);
    bf16x8 af[4][2], bfr[2][2];
    #pragma unroll
    for (int n = 0; n < 2; ++n)
      #pragma unroll
      for (int kk = 0; kk < 2; ++kk) {
        int row = wc * 32 + n * 16 + lr;
        bfr[n][kk] = *(const bf16x8*)(BsT + row * 128 + ((kk * 64 + kg * 16) ^ swz));
      }
    #pragma unroll
    for (int m = 0; m < 4; ++m)
      #pragma unroll
      for (int kk = 0; kk < 2; ++kk) {
        int row = wr * 128 + m * 16 + lr;
        af[m][kk] = *(const bf16x8*)(AsT + row * 128 + ((kk * 64 + kg * 16) ^ swz));
      }
    __builtin_amdgcn_s_setprio(1);
    #pragma unroll
    for (int m = 0; m < 4; ++m)
      #pragma unroll
      for (int n = 0; n < 2; ++n)
        #pragma unroll
        for (int kk = 0; kk < 2; ++kk)
          acc[m][n] = __builtin_amdgcn_mfma_f32_16x16x32_bf16(af[m][kk], bfr[n][kk], acc[m][n], 0, 0, 0);
    __builtin_amdgcn_s_setprio(0);

    // ---- phase 1: stage B(t+2), compute rows 64-127 ----
    if (t + 2 < NKT) stageB(t + 2, sb);
    #pragma unroll
    for (int m = 0; m < 4; ++m)
      #pragma unroll
      for (int kk = 0; kk < 2; ++kk) {
        int row = wr * 128 + (4 + m) * 16 + lr;
        af[m][kk] = *(const bf16x8*)(AsT + row * 128 + ((kk * 64 + kg * 16) ^ swz));
      }
    __builtin_amdgcn_s_setprio(1);
    #pragma unroll
    for (int m = 0; m < 4; ++m)
      #pragma unroll
      for (int n = 0; n < 2; ++n)
        #pragma unroll
        for (int kk = 0; kk < 2; ++kk)
          acc[4 + m][n] = __builtin_amdgcn_mfma_f32_16x16x32_bf16(af[m][kk], bfr[n][kk], acc[4 + m][n], 0, 0, 0);
    __builtin_amdgcn_s_setprio(0);

    // ---- boundary: counted vmcnt (T4), raw barrier ----
    if (t < NKT - 1) {
      if (t < NKT - 2) asm volatile("s_waitcnt vmcnt(6)" ::: "memory");
      else             asm volatile("s_waitcnt vmcnt(0)" ::: "memory");
      __builtin_amdgcn_s_barrier();
    }
    cb = (cb == 2) ? 0 : cb + 1;
  }

  // ---- epilogue: split output at col 1024 (for fused KV GEMM) ----
  const float* bias; char* outp; int ocol0;
  if (bcol < 1024) { bias = bias0; outp = (char*)out0; ocol0 = bcol; }
  else             { bias = bias1; outp = (char*)out1; ocol0 = bcol - 1024; }
  const int rq = (lane >> 4) * 4;
  #pragma unroll
  for (int n = 0; n < 2; ++n) {
    int oc = ocol0 + wc * 32 + n * 16 + lr;
    float bb = bias[oc];
    #pragma unroll
    for (int m = 0; m < 8; ++m) {
      int row = brow + wr * 128 + m * 16 + rq;
      #pragma unroll
      for (int r = 0; r < 4; ++r) {
        float v = acc[m][n][r] + bb;
        if (OUT_BF16)
          ((unsigned short*)outp)[(size_t)(row + r) * 1024 + oc] = f2bf(v);
        else
          ((float*)outp)[(size_t)(row + r) * 1024 + oc] = v;
      }
    }
  }
}

// ---------------- per-sample 8x8 cross-head attention ------------------------
__global__ __launch_bounds__(256) void attn_k(const unsigned short* __restrict__ Q,
                                              const unsigned short* __restrict__ Kc,
                                              const unsigned short* __restrict__ V,
                                              unsigned short* __restrict__ ctx) {
  __shared__ __align__(16) unsigned short sm[4][3][NH][136];
  const int wid = threadIdx.x >> 6, lane = threadIdx.x & 63;
  const int b = (blockIdx.x << 2) + wid;

  const unsigned short* bases[3] = { Q + (size_t)b * DIMSZ,
                                     Kc + (size_t)b * DIMSZ,
                                     V + (size_t)b * DIMSZ };
  const int row = lane >> 3, ch = lane & 7;
  #pragma unroll
  for (int m = 0; m < 3; ++m) {
    ushort8v v0 = *(const ushort8v*)(bases[m] + row * HD + ch * 16);
    ushort8v v1 = *(const ushort8v*)(bases[m] + row * HD + ch * 16 + 8);
    *(ushort8v*)&sm[wid][m][row][ch * 16] = v0;
    *(ushort8v*)&sm[wid][m][row][ch * 16 + 8] = v1;
  }
  __syncthreads();

  const int h = lane >> 3, g = lane & 7;
  const unsigned short* qr = &sm[wid][0][h][0];
  const unsigned short* kr = &sm[wid][1][g][0];
  float s = 0.f;
  #pragma unroll
  for (int c = 0; c < 16; ++c) {
    ushort8v qv = *(const ushort8v*)(qr + c * 8);
    ushort8v kv = *(const ushort8v*)(kr + c * 8);
    #pragma unroll
    for (int j = 0; j < 8; ++j) s += bf2f(qv[j]) * bf2f(kv[j]);
  }
  s *= 0.088388347648318447f;

  float mx = s;
  #pragma unroll
  for (int o = 1; o < 8; o <<= 1) mx = fmaxf(mx, __shfl_xor(mx, o));
  float e = __expf(s - mx);
  float sum = e;
  #pragma unroll
  for (int o = 1; o < 8; o <<= 1) sum += __shfl_xor(sum, o);
  float attn = e / sum;

  const int h2 = lane >> 3, d0 = (lane & 7) * 16;
  float cacc[16];
  #pragma unroll
  for (int j = 0; j < 16; ++j) cacc[j] = 0.f;
  #pragma unroll
  for (int g2 = 0; g2 < 8; ++g2) {
    float a = __shfl(attn, (lane & 56) + g2);
    const unsigned short* vr = &sm[wid][2][g2][d0];
    ushort8v v0 = *(const ushort8v*)vr;
    ushort8v v1 = *(const ushort8v*)(vr + 8);
    #pragma unroll
    for (int j = 0; j < 8; ++j) {
      cacc[j]     += a * bf2f(v0[j]);
      cacc[8 + j] += a * bf2f(v1[j]);
    }
  }
  ushort8v o0, o1;
  #pragma unroll
  for (int j = 0; j < 8; ++j) { o0[j] = f2bf(cacc[j]); o1[j] = f2bf(cacc[8 + j]); }
  unsigned short* op = ctx + (size_t)b * DIMSZ + h2 * HD + d0;
  *(ushort8v*)op = o0;
  *(ushort8v*)(op + 8) = o1;
}

// ---------------- launcher ---------------------------------------------------
extern "C" void kernel_launch(void* const* d_in, const int* in_sizes, int n_in,
                              void* d_out, int out_size, void* d_ws, size_t ws_size,
                              hipStream_t stream) {
  const float* feat1 = (const float*)d_in[0];
  const float* feat2 = (const float*)d_in[1];
  const float* Wq = (const float*)d_in[2];
  const float* bq = (const float*)d_in[3];
  const float* Wk = (const float*)d_in[4];
  const float* bk = (const float*)d_in[5];
  const float* Wv = (const float*)d_in[6];
  const float* bv = (const float*)d_in[7];
  const float* Wo = (const float*)d_in[8];
  const float* bo = (const float*)d_in[9];
  float* out = (float*)d_out;

  const int M = B_ROWS;
  char* ws = (char*)d_ws;
  const size_t featB = (size_t)M * DIMSZ * 2;   // 32 MB
  const size_t wB = (size_t)DIMSZ * DIMSZ * 2;  // 2 MB
  unsigned short* f1b = (unsigned short*)(ws);
  unsigned short* f2b = (unsigned short*)(ws + featB);
  unsigned short* Qb  = (unsigned short*)(ws + 2 * featB);
  unsigned short* Kb  = (unsigned short*)(ws + 3 * featB);
  unsigned short* Vb  = (unsigned short*)(ws + 4 * featB);
  unsigned short* Wqt = (unsigned short*)(ws + 5 * featB);
  unsigned short* Wkt = (unsigned short*)(ws + 5 * featB + wB);   // Wkt,Wvt adjacent:
  unsigned short* Wvt = (unsigned short*)(ws + 5 * featB + 2 * wB); // = Bt[2048][1024]
  unsigned short* Wot = (unsigned short*)(ws + 5 * featB + 3 * wB);
  unsigned short* ctx = f1b;   // f1b dead after Q GEMM

  const int n8 = M * DIMSZ / 8;
  cvt_f32_bf16_k<<<(n8 + 255) / 256, 256, 0, stream>>>(feat1, f1b, n8);
  cvt_f32_bf16_k<<<(n8 + 255) / 256, 256, 0, stream>>>(feat2, f2b, n8);

  dim3 tg(DIMSZ / 32, DIMSZ / 32);
  transpose_cvt_k<<<tg, 256, 0, stream>>>(Wq, Wqt, DIMSZ, DIMSZ);
  transpose_cvt_k<<<tg, 256, 0, stream>>>(Wk, Wkt, DIMSZ, DIMSZ);
  transpose_cvt_k<<<tg, 256, 0, stream>>>(Wv, Wvt, DIMSZ, DIMSZ);
  transpose_cvt_k<<<tg, 256, 0, stream>>>(Wo, Wot, DIMSZ, DIMSZ);

  // Q: N=1024
  gemm2_k<1024, 1><<<(M / 256) * 8, 512, 0, stream>>>(f1b, Wqt, bq, bq, Qb, Qb);
  // K,V fused: N=2048, split epilogue
  gemm2_k<2048, 1><<<(M / 256) * 16, 512, 0, stream>>>(f2b, Wkt, bk, bv, Kb, Vb);

  attn_k<<<M / 4, 256, 0, stream>>>(Qb, Kb, Vb, ctx);

  // output projection: fp32 out
  gemm2_k<1024, 0><<<(M / 256) * 8, 512, 0, stream>>>(ctx, Wot, bo, bo, out, out);
}

// Round 3
// 241.948 us; speedup vs baseline: 1.3460x; 1.0184x over previous
//
#include <hip/hip_runtime.h>
#include <cstdint>
#include <cstddef>

#define B_ROWS 16384
#define DIMSZ  1024
#define NH     8
#define HD     128
#define KDIM   1024

typedef __attribute__((ext_vector_type(8))) __bf16 bf16x8;
typedef __attribute__((ext_vector_type(4))) float f32x4;
typedef __attribute__((ext_vector_type(8))) unsigned short ushort8v;

__device__ __forceinline__ unsigned short f2bf(float f) {
  union { float f; unsigned int u; } x; x.f = f;
  unsigned int r = x.u + 0x7FFFu + ((x.u >> 16) & 1u);   // RNE
  return (unsigned short)(r >> 16);
}
__device__ __forceinline__ float bf2f(unsigned short h) {
  union { unsigned int u; float f; } x; x.u = ((unsigned int)h) << 16;
  return x.f;
}

__device__ __forceinline__ void gload_lds16(const void* g, void* l) {
  __builtin_amdgcn_global_load_lds(
      (__attribute__((address_space(1))) void*)(uintptr_t)g,
      (__attribute__((address_space(3))) void*)(uintptr_t)l, 16, 0, 0);
}

// Inverse of the LDS read swizzle  L -> L ^ (((L>>6)&7)<<4)  (bits 4-6 mixed
// from row bits).  Derivation: b4'=b4^b6, b5'=b5^b7, b6'=b6^b8 (triangular,
// bijective); inverse: b6=D6^D8, b5=D5^D7, b4=D4^D6^D8.
__device__ __forceinline__ int inv_swz(int D) {
  return D ^ ((((D >> 6) ^ (D >> 8)) & 1) << 4) ^ (((D >> 7) & 1) << 5)
           ^ (((D >> 8) & 1) << 6);
}

// ---------------- fp32 -> bf16 convert (both features, one launch) -----------
__global__ __launch_bounds__(256) void cvt2_k(const float* __restrict__ a,
                                              const float* __restrict__ b,
                                              unsigned short* __restrict__ oa,
                                              unsigned short* __restrict__ ob,
                                              int n8each) {
  int i = blockIdx.x * 256 + threadIdx.x;
  const float* src; unsigned short* dst; int j;
  if (i < n8each) { src = a; dst = oa; j = i; }
  else            { src = b; dst = ob; j = i - n8each; }
  const float4* p = (const float4*)src + 2 * (size_t)j;
  float4 x = p[0], y = p[1];
  ushort8v o;
  o[0] = f2bf(x.x); o[1] = f2bf(x.y); o[2] = f2bf(x.z); o[3] = f2bf(x.w);
  o[4] = f2bf(y.x); o[5] = f2bf(y.y); o[6] = f2bf(y.z); o[7] = f2bf(y.w);
  *(ushort8v*)(dst + 8 * (size_t)j) = o;
}

// ---------------- all 4 weight transposes, one launch ------------------------
__global__ __launch_bounds__(256) void transpose_cvt4_k(
    const float* __restrict__ W0, const float* __restrict__ W1,
    const float* __restrict__ W2, const float* __restrict__ W3,
    unsigned short* __restrict__ T0, unsigned short* __restrict__ T1,
    unsigned short* __restrict__ T2, unsigned short* __restrict__ T3) {
  const float* W; unsigned short* T;
  switch (blockIdx.z) {
    case 0: W = W0; T = T0; break;
    case 1: W = W1; T = T1; break;
    case 2: W = W2; T = T2; break;
    default: W = W3; T = T3; break;
  }
  __shared__ float tile[32][33];
  int bx = blockIdx.x * 32, by = blockIdx.y * 32;
  int tx = threadIdx.x & 31, ty = threadIdx.x >> 5;
  #pragma unroll
  for (int j = ty; j < 32; j += 8)
    tile[j][tx] = W[(size_t)(by + j) * DIMSZ + bx + tx];
  __syncthreads();
  #pragma unroll
  for (int j = ty; j < 32; j += 8)
    T[(size_t)(bx + j) * DIMSZ + by + tx] = f2bf(tile[tx][j]);
}

// ---------------- pipelined bf16 MFMA GEMM -----------------------------------
// C[M,NCOLS] = A[M,K] @ Bt[NCOLS,K]^T + bias.
// Tile 256x256, BK=32, 8 waves (2x4), per-wave 128x64 (43 FLOP per LDS byte),
// 3-deep LDS pipeline, counted vmcnt(4), XOR-swizzled LDS reads with
// inverse-swizzled global staging, setprio around MFMA clusters, XCD swizzle.
template <int NCOLS, int OUT_BF16>
__global__ __launch_bounds__(512, 2) void gemm3_k(
    const unsigned short* __restrict__ A,
    const unsigned short* __restrict__ Bt,
    const float* __restrict__ bias0, const float* __restrict__ bias1,
    void* __restrict__ out0, void* __restrict__ out1) {
  constexpr int NBC = NCOLS / 256;
  constexpr int NWG = (B_ROWS / 256) * NBC;
  constexpr int NKT = KDIM / 32;   // 32 K-tiles

  // 3 x (A 256x32 = 16KB) + 3 x (B 256x32 = 16KB) = 96 KiB
  __shared__ __align__(16) unsigned short lds[6 * 8192];

  const int tid = threadIdx.x;
  const int wid = tid >> 6, lane = tid & 63;
  const int lr = lane & 15, kg = lane >> 4;
  const int wr = wid >> 2, wc = wid & 3;
  const int swz = (lane & 7) << 4;

  // T1: XCD-aware block swizzle (NWG % 8 == 0 for all instantiations)
  const int x = ((int)blockIdx.x % 8) * (NWG / 8) + (int)blockIdx.x / 8;
  const int bcol = (x % NBC) * 256;
  const int brow = (x / NBC) * 256;

  const char* Ab = (const char*)(A + (size_t)brow * KDIM);
  const char* Bb = (const char*)(Bt + (size_t)bcol * KDIM);
  char* AsBase = (char*)lds;             // 3 x 16KB
  char* BsBase = (char*)lds + 49152;     // 3 x 16KB

  // stage one K-tile operand (16KB): linear LDS dest, inverse-swizzled source
  auto stageA = [&](int t, int buf) {
    char* dstb = AsBase + (buf << 14);
    #pragma unroll
    for (int r = 0; r < 2; ++r) {
      int base = (r * 8 + wid) << 10;
      int L = inv_swz(base + (lane << 4));
      const char* src = Ab + (size_t)(L >> 6) * 2048 + (t << 6) + (L & 48);
      gload_lds16(src, dstb + base);
    }
  };
  auto stageB = [&](int t, int buf) {
    char* dstb = BsBase + (buf << 14);
    #pragma unroll
    for (int r = 0; r < 2; ++r) {
      int base = (r * 8 + wid) << 10;
      int L = inv_swz(base + (lane << 4));
      const char* src = Bb + (size_t)(L >> 6) * 2048 + (t << 6) + (L & 48);
      gload_lds16(src, dstb + base);
    }
  };

  f32x4 acc[8][4] = {};

  // prologue: tiles 0,1 in flight; drain tile0's 4 loads, keep tile1's 4
  stageA(0, 0); stageB(0, 0);
  stageA(1, 1); stageB(1, 1);
  asm volatile("s_waitcnt vmcnt(4)" ::: "memory");
  __builtin_amdgcn_s_barrier();

  int cb = 0;
  #pragma unroll 1
  for (int t = 0; t < NKT; ++t) {
    const char* AsT = AsBase + (cb << 14);
    const char* BsT = BsBase + (cb << 14);
    int sb = cb + 2; if (sb >= 3) sb -= 3;

    // ---- stage A(t+2); read all B frags + A frags m0-3; 16 MFMA ----
    if (t + 2 < NKT) stageA(t + 2, sb);
    bf16x8 bfr[4], af[4];
    #pragma unroll
    for (int n = 0; n < 4; ++n) {
      int row = wc * 64 + n * 16 + lr;
      bfr[n] = *(const bf16x8*)(BsT + (((row << 6) + (kg << 4)) ^ swz));
    }
    #pragma unroll
    for (int m = 0; m < 4; ++m) {
      int row = wr * 128 + m * 16 + lr;
      af[m] = *(const bf16x8*)(AsT + (((row << 6) + (kg << 4)) ^ swz));
    }
    __builtin_amdgcn_s_setprio(1);
    #pragma unroll
    for (int m = 0; m < 4; ++m)
      #pragma unroll
      for (int n = 0; n < 4; ++n)
        acc[m][n] = __builtin_amdgcn_mfma_f32_16x16x32_bf16(af[m], bfr[n], acc[m][n], 0, 0, 0);
    __builtin_amdgcn_s_setprio(0);

    // ---- stage B(t+2); read A frags m4-7; 16 MFMA ----
    if (t + 2 < NKT) stageB(t + 2, sb);
    #pragma unroll
    for (int m = 0; m < 4; ++m) {
      int row = wr * 128 + (m + 4) * 16 + lr;
      af[m] = *(const bf16x8*)(AsT + (((row << 6) + (kg << 4)) ^ swz));
    }
    __builtin_amdgcn_s_setprio(1);
    #pragma unroll
    for (int m = 0; m < 4; ++m)
      #pragma unroll
      for (int n = 0; n < 4; ++n)
        acc[m + 4][n] = __builtin_amdgcn_mfma_f32_16x16x32_bf16(af[m], bfr[n], acc[m + 4][n], 0, 0, 0);
    __builtin_amdgcn_s_setprio(0);

    // ---- boundary: counted vmcnt (T4), raw barrier ----
    if (t < NKT - 1) {
      if (t < NKT - 2) asm volatile("s_waitcnt vmcnt(4)" ::: "memory");
      else             asm volatile("s_waitcnt vmcnt(0)" ::: "memory");
      __builtin_amdgcn_s_barrier();
    }
    cb = (cb == 2) ? 0 : cb + 1;
  }

  // ---- epilogue: split output at col 1024 (for fused KV GEMM) ----
  const float* bias; char* outp; int ocol0;
  if (NCOLS == 1024 || bcol < 1024) { bias = bias0; outp = (char*)out0; ocol0 = bcol; }
  else                              { bias = bias1; outp = (char*)out1; ocol0 = bcol - 1024; }
  const int rq = kg * 4;
  #pragma unroll
  for (int n = 0; n < 4; ++n) {
    int oc = ocol0 + wc * 64 + n * 16 + lr;
    float bb = bias[oc];
    #pragma unroll
    for (int m = 0; m < 8; ++m) {
      int row = brow + wr * 128 + m * 16 + rq;
      #pragma unroll
      for (int r = 0; r < 4; ++r) {
        float v = acc[m][n][r] + bb;
        if (OUT_BF16)
          ((unsigned short*)outp)[(size_t)(row + r) * 1024 + oc] = f2bf(v);
        else
          ((float*)outp)[(size_t)(row + r) * 1024 + oc] = v;
      }
    }
  }
}

// ---------------- per-sample 8x8 cross-head attention ------------------------
__global__ __launch_bounds__(256) void attn_k(const unsigned short* __restrict__ Q,
                                              const unsigned short* __restrict__ Kc,
                                              const unsigned short* __restrict__ V,
                                              unsigned short* __restrict__ ctx) {
  __shared__ __align__(16) unsigned short sm[4][3][NH][136];
  const int wid = threadIdx.x >> 6, lane = threadIdx.x & 63;
  const int b = (blockIdx.x << 2) + wid;

  const unsigned short* bases[3] = { Q + (size_t)b * DIMSZ,
                                     Kc + (size_t)b * DIMSZ,
                                     V + (size_t)b * DIMSZ };
  const int row = lane >> 3, ch = lane & 7;
  #pragma unroll
  for (int m = 0; m < 3; ++m) {
    ushort8v v0 = *(const ushort8v*)(bases[m] + row * HD + ch * 16);
    ushort8v v1 = *(const ushort8v*)(bases[m] + row * HD + ch * 16 + 8);
    *(ushort8v*)&sm[wid][m][row][ch * 16] = v0;
    *(ushort8v*)&sm[wid][m][row][ch * 16 + 8] = v1;
  }
  __syncthreads();

  const int h = lane >> 3, g = lane & 7;
  const unsigned short* qr = &sm[wid][0][h][0];
  const unsigned short* kr = &sm[wid][1][g][0];
  float s = 0.f;
  #pragma unroll
  for (int c = 0; c < 16; ++c) {
    ushort8v qv = *(const ushort8v*)(qr + c * 8);
    ushort8v kv = *(const ushort8v*)(kr + c * 8);
    #pragma unroll
    for (int j = 0; j < 8; ++j) s += bf2f(qv[j]) * bf2f(kv[j]);
  }
  s *= 0.088388347648318447f;

  float mx = s;
  #pragma unroll
  for (int o = 1; o < 8; o <<= 1) mx = fmaxf(mx, __shfl_xor(mx, o));
  float e = __expf(s - mx);
  float sum = e;
  #pragma unroll
  for (int o = 1; o < 8; o <<= 1) sum += __shfl_xor(sum, o);
  float attn = e / sum;

  const int h2 = lane >> 3, d0 = (lane & 7) * 16;
  float cacc[16];
  #pragma unroll
  for (int j = 0; j < 16; ++j) cacc[j] = 0.f;
  #pragma unroll
  for (int g2 = 0; g2 < 8; ++g2) {
    float a = __shfl(attn, (lane & 56) + g2);
    const unsigned short* vr = &sm[wid][2][g2][d0];
    ushort8v v0 = *(const ushort8v*)vr;
    ushort8v v1 = *(const ushort8v*)(vr + 8);
    #pragma unroll
    for (int j = 0; j < 8; ++j) {
      cacc[j]     += a * bf2f(v0[j]);
      cacc[8 + j] += a * bf2f(v1[j]);
    }
  }
  ushort8v o0, o1;
  #pragma unroll
  for (int j = 0; j < 8; ++j) { o0[j] = f2bf(cacc[j]); o1[j] = f2bf(cacc[8 + j]); }
  unsigned short* op = ctx + (size_t)b * DIMSZ + h2 * HD + d0;
  *(ushort8v*)op = o0;
  *(ushort8v*)(op + 8) = o1;
}

// ---------------- launcher ---------------------------------------------------
extern "C" void kernel_launch(void* const* d_in, const int* in_sizes, int n_in,
                              void* d_out, int out_size, void* d_ws, size_t ws_size,
                              hipStream_t stream) {
  const float* feat1 = (const float*)d_in[0];
  const float* feat2 = (const float*)d_in[1];
  const float* Wq = (const float*)d_in[2];
  const float* bq = (const float*)d_in[3];
  const float* Wk = (const float*)d_in[4];
  const float* bk = (const float*)d_in[5];
  const float* Wv = (const float*)d_in[6];
  const float* bv = (const float*)d_in[7];
  const float* Wo = (const float*)d_in[8];
  const float* bo = (const float*)d_in[9];
  float* out = (float*)d_out;

  const int M = B_ROWS;
  char* ws = (char*)d_ws;
  const size_t featB = (size_t)M * DIMSZ * 2;   // 32 MB
  const size_t wB = (size_t)DIMSZ * DIMSZ * 2;  // 2 MB
  unsigned short* f1b = (unsigned short*)(ws);
  unsigned short* f2b = (unsigned short*)(ws + featB);
  unsigned short* Qb  = (unsigned short*)(ws + 2 * featB);
  unsigned short* Kb  = (unsigned short*)(ws + 3 * featB);
  unsigned short* Vb  = (unsigned short*)(ws + 4 * featB);
  unsigned short* Wqt = (unsigned short*)(ws + 5 * featB);
  unsigned short* Wkt = (unsigned short*)(ws + 5 * featB + wB);   // Wkt,Wvt adjacent
  unsigned short* Wvt = (unsigned short*)(ws + 5 * featB + 2 * wB);
  unsigned short* Wot = (unsigned short*)(ws + 5 * featB + 3 * wB);
  unsigned short* ctx = f1b;   // f1b dead after Q GEMM

  const int n8 = M * DIMSZ / 8;
  cvt2_k<<<(2 * n8 + 255) / 256, 256, 0, stream>>>(feat1, feat2, f1b, f2b, n8);
  transpose_cvt4_k<<<dim3(32, 32, 4), 256, 0, stream>>>(Wq, Wk, Wv, Wo,
                                                        Wqt, Wkt, Wvt, Wot);

  // Q: N=1024 (256 blocks), KV fused: N=2048 (512 blocks)
  gemm3_k<1024, 1><<<256, 512, 0, stream>>>(f1b, Wqt, bq, bq, Qb, Qb);
  gemm3_k<2048, 1><<<512, 512, 0, stream>>>(f2b, Wkt, bk, bv, Kb, Vb);

  attn_k<<<M / 4, 256, 0, stream>>>(Qb, Kb, Vb, ctx);

  // output projection: fp32 out
  gemm3_k<1024, 0><<<256, 512, 0, stream>>>(ctx, Wot, bo, bo, out, out);
}

// Round 4
// 234.692 us; speedup vs baseline: 1.3877x; 1.0309x over previous
//
#include <hip/hip_runtime.h>
#include <cstdint>
#include <cstddef>

#define B_ROWS 16384
#define DIMSZ  1024
#define NH     8
#define HD     128
#define KDIM   1024

typedef __attribute__((ext_vector_type(8))) __bf16 bf16x8;
typedef __attribute__((ext_vector_type(4))) float f32x4;
typedef __attribute__((ext_vector_type(8))) unsigned short ushort8v;

__device__ __forceinline__ unsigned short f2bf(float f) {
  union { float f; unsigned int u; } x; x.f = f;
  unsigned int r = x.u + 0x7FFFu + ((x.u >> 16) & 1u);   // RNE
  return (unsigned short)(r >> 16);
}
__device__ __forceinline__ float bf2f(unsigned short h) {
  union { unsigned int u; float f; } x; x.u = ((unsigned int)h) << 16;
  return x.f;
}

__device__ __forceinline__ void gload_lds16(const void* g, void* l) {
  __builtin_amdgcn_global_load_lds(
      (__attribute__((address_space(1))) void*)(uintptr_t)g,
      (__attribute__((address_space(3))) void*)(uintptr_t)l, 16, 0, 0);
}

// ---------------- fp32 -> bf16 convert (both features, one launch) -----------
__global__ __launch_bounds__(256) void cvt2_k(const float* __restrict__ a,
                                              const float* __restrict__ b,
                                              unsigned short* __restrict__ oa,
                                              unsigned short* __restrict__ ob,
                                              int n8each) {
  int i = blockIdx.x * 256 + threadIdx.x;
  const float* src; unsigned short* dst; int j;
  if (i < n8each) { src = a; dst = oa; j = i; }
  else            { src = b; dst = ob; j = i - n8each; }
  const float4* p = (const float4*)src + 2 * (size_t)j;
  float4 x = p[0], y = p[1];
  ushort8v o;
  o[0] = f2bf(x.x); o[1] = f2bf(x.y); o[2] = f2bf(x.z); o[3] = f2bf(x.w);
  o[4] = f2bf(y.x); o[5] = f2bf(y.y); o[6] = f2bf(y.z); o[7] = f2bf(y.w);
  *(ushort8v*)(dst + 8 * (size_t)j) = o;
}

// ---------------- all 4 weight transposes, one launch ------------------------
__global__ __launch_bounds__(256) void transpose_cvt4_k(
    const float* __restrict__ W0, const float* __restrict__ W1,
    const float* __restrict__ W2, const float* __restrict__ W3,
    unsigned short* __restrict__ T0, unsigned short* __restrict__ T1,
    unsigned short* __restrict__ T2, unsigned short* __restrict__ T3) {
  const float* W; unsigned short* T;
  switch (blockIdx.z) {
    case 0: W = W0; T = T0; break;
    case 1: W = W1; T = T1; break;
    case 2: W = W2; T = T2; break;
    default: W = W3; T = T3; break;
  }
  __shared__ float tile[32][33];
  int bx = blockIdx.x * 32, by = blockIdx.y * 32;
  int tx = threadIdx.x & 31, ty = threadIdx.x >> 5;
  #pragma unroll
  for (int j = ty; j < 32; j += 8)
    tile[j][tx] = W[(size_t)(by + j) * DIMSZ + bx + tx];
  __syncthreads();
  #pragma unroll
  for (int j = ty; j < 32; j += 8)
    T[(size_t)(bx + j) * DIMSZ + by + tx] = f2bf(tile[tx][j]);
}

// ---------------- 8-phase pipelined bf16 MFMA GEMM (m201-style) --------------
// C[M,NCOLS] = A[M,K] @ Bt[NCOLS,K]^T + bias.
// BM=BN=256, BK=64, 8 waves (2x4), per-wave 128x64, acc[8][4].
// LDS 128 KiB: per dbuf d (2), per operand, 2 units of 16KB (128 rows x 128B).
//   A unit u = tile rows with bit6==u (each wave's m0-3 / m4-7 frag rows).
//   B unit u = tile rows with bit5==u (n0-1 / n2-3 frag rows).
// Swizzle (R2-proven, 0 conflicts): within-128B-row XOR, D ^= ((D>>7)&7)<<4
// (involution; staged via inverse-permuted global source, rule #21).
// Phase schedule per K-tile t (dbuf cb=t&1), 16 MFMA each:
//   ph1: read A-u0(8) + B-u0(4);              MFMA m0-3 x n0-1
//   ph2: read B-u1(4); stage A0,B0(t+2)->cb;  MFMA m0-3 x n2-3
//   ph3: read A-u1(8); stage B1(t+2)->cb;     MFMA m4-7 x n0-1
//   ph4:               stage A1(t+2)->cb;     MFMA m4-7 x n2-3
//   boundary: vmcnt(8) [=leave t+2's 8 loads in flight], s_barrier
// Race ledger: WAR -- unit X(t+2) staged the phase AFTER X(t)'s only read
// phase; all waves' phase-p ds_reads complete before p's MFMA (lgkmcnt 0) and
// the end-of-phase barrier publishes that chip-wide. RAW -- all of t+1's units
// are issued during t-1, so boundary vmcnt(8) (= all but t's issues) covers
// them. Prologue stages T0+T1 fully (16 loads), vmcnt(8) leaves T1 in flight.
template <int NCOLS, int OUT_BF16>
__global__ __launch_bounds__(512, 2) void gemm4_k(
    const unsigned short* __restrict__ A,
    const unsigned short* __restrict__ Bt,
    const float* __restrict__ bias0, const float* __restrict__ bias1,
    void* __restrict__ out0, void* __restrict__ out1) {
  constexpr int NBC = NCOLS / 256;
  constexpr int NWG = (B_ROWS / 256) * NBC;
  constexpr int NKT = KDIM / 64;   // 16

  __shared__ __align__(16) char lds[131072];
  // A units at ((d*2+u)<<14); B units at 65536 + ((d*2+u)<<14)

  const int tid = threadIdx.x;
  const int wid = tid >> 6, lane = tid & 63;
  const int lr = lane & 15, kg = lane >> 4;
  const int wr = wid >> 2, wc = wid & 3;
  const int swz = (lr & 7) << 4;

  // T1: XCD-aware block swizzle (NWG % 8 == 0 for all instantiations)
  const int x = ((int)blockIdx.x % 8) * (NWG / 8) + (int)blockIdx.x / 8;
  const int bcol = (x % NBC) * 256;
  const int brow = (x / NBC) * 256;

  const char* Ab = (const char*)(A + (size_t)brow * KDIM);
  const char* Bb = (const char*)(Bt + (size_t)bcol * KDIM);

  // per-thread staging offsets: dest byte D = j*8192 + tid*16 (linear, 2 loads
  // per 16KB unit); source L = D ^ ((D>>7)&7)<<4; unpack packed-row -> global.
  int aof[2][2], bof[2][2];
  #pragma unroll
  for (int u = 0; u < 2; ++u)
    #pragma unroll
    for (int j = 0; j < 2; ++j) {
      int D = j * 8192 + tid * 16;
      int L = D ^ (((D >> 7) & 7) << 4);
      int pr = L >> 7, c = L & 127;
      int grA = (pr & 63) | ((pr >> 6) << 7) | (u << 6);
      int grB = (pr & 31) | ((pr >> 5) << 6) | (u << 5);
      aof[u][j] = grA * 2048 + c;
      bof[u][j] = grB * 2048 + c;
    }
  const int aof00 = aof[0][0], aof01 = aof[0][1], aof10 = aof[1][0], aof11 = aof[1][1];
  const int bof00 = bof[0][0], bof01 = bof[0][1], bof10 = bof[1][0], bof11 = bof[1][1];

  #define STG_A(u, o0, o1, t_, cb_) do {                                   \
    char* dst_ = lds + (((cb_) * 2 + (u)) << 14) + tid * 16;               \
    gload_lds16(Ab + (o0) + (t_) * 128, dst_);                             \
    gload_lds16(Ab + (o1) + (t_) * 128, dst_ + 8192); } while (0)
  #define STG_B(u, o0, o1, t_, cb_) do {                                   \
    char* dst_ = lds + 65536 + (((cb_) * 2 + (u)) << 14) + tid * 16;       \
    gload_lds16(Bb + (o0) + (t_) * 128, dst_);                             \
    gload_lds16(Bb + (o1) + (t_) * 128, dst_ + 8192); } while (0)

  // per-thread LDS read bases (within a unit): row pr, col (kk*64+kg*16)^swz
  const int ardbase = (wr * 64 + lr) * 128;      // + (m&3)*16*128
  const int brdbase = (wc * 32 + lr) * 128;      // + (n&1)*16*128
  const int col0 = (kg * 16) ^ swz, col1 = (64 + kg * 16) ^ swz;

  f32x4 acc[8][4] = {};
  bf16x8 afr[4][2], bfr[4][2];

  // ---- prologue: T0 (dbuf0) + T1 (dbuf1) fully staged; T0 drained ----
  #pragma unroll
  for (int d = 0; d < 2; ++d) {
    STG_A(0, aof00, aof01, d, d);
    STG_B(0, bof00, bof01, d, d);
    STG_B(1, bof10, bof11, d, d);
    STG_A(1, aof10, aof11, d, d);
  }
  asm volatile("s_waitcnt vmcnt(8)" ::: "memory");
  __builtin_amdgcn_s_barrier();

  #pragma unroll 1
  for (int t = 0; t < NKT; ++t) {
    const int cb = t & 1;
    const char* Au0 = lds + ((cb * 2 + 0) << 14);
    const char* Au1 = lds + ((cb * 2 + 1) << 14);
    const char* Bu0 = lds + 65536 + ((cb * 2 + 0) << 14);
    const char* Bu1 = lds + 65536 + ((cb * 2 + 1) << 14);
    const bool st = (t + 2 < NKT);

    // ---------- phase 1: read A-u0 (8) + B-u0 (4); MFMA m0-3 x n0-1 ----------
    #pragma unroll
    for (int n = 0; n < 2; ++n) {
      int rb = brdbase + n * 2048;
      bfr[n][0] = *(const bf16x8*)(Bu0 + rb + col0);
      bfr[n][1] = *(const bf16x8*)(Bu0 + rb + col1);
    }
    #pragma unroll
    for (int m = 0; m < 4; ++m) {
      int rb = ardbase + m * 2048;
      afr[m][0] = *(const bf16x8*)(Au0 + rb + col0);
      afr[m][1] = *(const bf16x8*)(Au0 + rb + col1);
    }
    __builtin_amdgcn_s_barrier();
    asm volatile("s_waitcnt lgkmcnt(0)" ::: "memory");
    __builtin_amdgcn_sched_barrier(0);
    __builtin_amdgcn_s_setprio(1);
    #pragma unroll
    for (int m = 0; m < 4; ++m)
      #pragma unroll
      for (int n = 0; n < 2; ++n) {
        acc[m][n] = __builtin_amdgcn_mfma_f32_16x16x32_bf16(afr[m][0], bfr[n][0], acc[m][n], 0, 0, 0);
        acc[m][n] = __builtin_amdgcn_mfma_f32_16x16x32_bf16(afr[m][1], bfr[n][1], acc[m][n], 0, 0, 0);
      }
    __builtin_amdgcn_s_setprio(0);
    __builtin_amdgcn_s_barrier();

    // ---------- phase 2: read B-u1 (4); stage A0,B0(t+2); MFMA m0-3 x n2-3 ---
    #pragma unroll
    for (int n = 0; n < 2; ++n) {
      int rb = brdbase + n * 2048;
      bfr[2 + n][0] = *(const bf16x8*)(Bu1 + rb + col0);
      bfr[2 + n][1] = *(const bf16x8*)(Bu1 + rb + col1);
    }
    if (st) { STG_A(0, aof00, aof01, t + 2, cb); STG_B(0, bof00, bof01, t + 2, cb); }
    __builtin_amdgcn_s_barrier();
    asm volatile("s_waitcnt lgkmcnt(0)" ::: "memory");
    __builtin_amdgcn_sched_barrier(0);
    __builtin_amdgcn_s_setprio(1);
    #pragma unroll
    for (int m = 0; m < 4; ++m)
      #pragma unroll
      for (int n = 0; n < 2; ++n) {
        acc[m][2 + n] = __builtin_amdgcn_mfma_f32_16x16x32_bf16(afr[m][0], bfr[2 + n][0], acc[m][2 + n], 0, 0, 0);
        acc[m][2 + n] = __builtin_amdgcn_mfma_f32_16x16x32_bf16(afr[m][1], bfr[2 + n][1], acc[m][2 + n], 0, 0, 0);
      }
    __builtin_amdgcn_s_setprio(0);
    __builtin_amdgcn_s_barrier();

    // ---------- phase 3: read A-u1 (8); stage B1(t+2); MFMA m4-7 x n0-1 ------
    #pragma unroll
    for (int m = 0; m < 4; ++m) {
      int rb = ardbase + m * 2048;
      afr[m][0] = *(const bf16x8*)(Au1 + rb + col0);
      afr[m][1] = *(const bf16x8*)(Au1 + rb + col1);
    }
    if (st) STG_B(1, bof10, bof11, t + 2, cb);
    __builtin_amdgcn_s_barrier();
    asm volatile("s_waitcnt lgkmcnt(0)" ::: "memory");
    __builtin_amdgcn_sched_barrier(0);
    __builtin_amdgcn_s_setprio(1);
    #pragma unroll
    for (int m = 0; m < 4; ++m)
      #pragma unroll
      for (int n = 0; n < 2; ++n) {
        acc[4 + m][n] = __builtin_amdgcn_mfma_f32_16x16x32_bf16(afr[m][0], bfr[n][0], acc[4 + m][n], 0, 0, 0);
        acc[4 + m][n] = __builtin_amdgcn_mfma_f32_16x16x32_bf16(afr[m][1], bfr[n][1], acc[4 + m][n], 0, 0, 0);
      }
    __builtin_amdgcn_s_setprio(0);
    __builtin_amdgcn_s_barrier();

    // ---------- phase 4: stage A1(t+2); MFMA m4-7 x n2-3 (regs only) ---------
    if (st) STG_A(1, aof10, aof11, t + 2, cb);
    __builtin_amdgcn_s_setprio(1);
    #pragma unroll
    for (int m = 0; m < 4; ++m)
      #pragma unroll
      for (int n = 0; n < 2; ++n) {
        acc[4 + m][2 + n] = __builtin_amdgcn_mfma_f32_16x16x32_bf16(afr[m][0], bfr[2 + n][0], acc[4 + m][2 + n], 0, 0, 0);
        acc[4 + m][2 + n] = __builtin_amdgcn_mfma_f32_16x16x32_bf16(afr[m][1], bfr[2 + n][1], acc[4 + m][2 + n], 0, 0, 0);
      }
    __builtin_amdgcn_s_setprio(0);

    // ---------- boundary: counted vmcnt, barrier ----------
    if (t < NKT - 1) {
      if (t < NKT - 2) asm volatile("s_waitcnt vmcnt(8)" ::: "memory");
      else             asm volatile("s_waitcnt vmcnt(0)" ::: "memory");
      __builtin_amdgcn_s_barrier();
    }
  }
  #undef STG_A
  #undef STG_B

  // ---- epilogue: split output at col 1024 (for fused KV GEMM) ----
  const float* bias; char* outp; int ocol0;
  if (NCOLS == 1024 || bcol < 1024) { bias = bias0; outp = (char*)out0; ocol0 = bcol; }
  else                              { bias = bias1; outp = (char*)out1; ocol0 = bcol - 1024; }
  const int rq = kg * 4;
  #pragma unroll
  for (int n = 0; n < 4; ++n) {
    int oc = ocol0 + wc * 64 + n * 16 + lr;
    float bb = bias[oc];
    #pragma unroll
    for (int m = 0; m < 8; ++m) {
      int row = brow + wr * 128 + m * 16 + rq;
      #pragma unroll
      for (int r = 0; r < 4; ++r) {
        float v = acc[m][n][r] + bb;
        if (OUT_BF16)
          ((unsigned short*)outp)[(size_t)(row + r) * 1024 + oc] = f2bf(v);
        else
          ((float*)outp)[(size_t)(row + r) * 1024 + oc] = v;
      }
    }
  }
}

// ---------------- per-sample 8x8 cross-head attention ------------------------
__global__ __launch_bounds__(256) void attn_k(const unsigned short* __restrict__ Q,
                                              const unsigned short* __restrict__ Kc,
                                              const unsigned short* __restrict__ V,
                                              unsigned short* __restrict__ ctx) {
  __shared__ __align__(16) unsigned short sm[4][3][NH][136];
  const int wid = threadIdx.x >> 6, lane = threadIdx.x & 63;
  const int b = (blockIdx.x << 2) + wid;

  const unsigned short* bases[3] = { Q + (size_t)b * DIMSZ,
                                     Kc + (size_t)b * DIMSZ,
                                     V + (size_t)b * DIMSZ };
  const int row = lane >> 3, ch = lane & 7;
  #pragma unroll
  for (int m = 0; m < 3; ++m) {
    ushort8v v0 = *(const ushort8v*)(bases[m] + row * HD + ch * 16);
    ushort8v v1 = *(const ushort8v*)(bases[m] + row * HD + ch * 16 + 8);
    *(ushort8v*)&sm[wid][m][row][ch * 16] = v0;
    *(ushort8v*)&sm[wid][m][row][ch * 16 + 8] = v1;
  }
  __syncthreads();

  const int h = lane >> 3, g = lane & 7;
  const unsigned short* qr = &sm[wid][0][h][0];
  const unsigned short* kr = &sm[wid][1][g][0];
  float s = 0.f;
  #pragma unroll
  for (int c = 0; c < 16; ++c) {
    ushort8v qv = *(const ushort8v*)(qr + c * 8);
    ushort8v kv = *(const ushort8v*)(kr + c * 8);
    #pragma unroll
    for (int j = 0; j < 8; ++j) s += bf2f(qv[j]) * bf2f(kv[j]);
  }
  s *= 0.088388347648318447f;

  float mx = s;
  #pragma unroll
  for (int o = 1; o < 8; o <<= 1) mx = fmaxf(mx, __shfl_xor(mx, o));
  float e = __expf(s - mx);
  float sum = e;
  #pragma unroll
  for (int o = 1; o < 8; o <<= 1) sum += __shfl_xor(sum, o);
  float attn = e / sum;

  const int h2 = lane >> 3, d0 = (lane & 7) * 16;
  float cacc[16];
  #pragma unroll
  for (int j = 0; j < 16; ++j) cacc[j] = 0.f;
  #pragma unroll
  for (int g2 = 0; g2 < 8; ++g2) {
    float a = __shfl(attn, (lane & 56) + g2);
    const unsigned short* vr = &sm[wid][2][g2][d0];
    ushort8v v0 = *(const ushort8v*)vr;
    ushort8v v1 = *(const ushort8v*)(vr + 8);
    #pragma unroll
    for (int j = 0; j < 8; ++j) {
      cacc[j]     += a * bf2f(v0[j]);
      cacc[8 + j] += a * bf2f(v1[j]);
    }
  }
  ushort8v o0, o1;
  #pragma unroll
  for (int j = 0; j < 8; ++j) { o0[j] = f2bf(cacc[j]); o1[j] = f2bf(cacc[8 + j]); }
  unsigned short* op = ctx + (size_t)b * DIMSZ + h2 * HD + d0;
  *(ushort8v*)op = o0;
  *(ushort8v*)(op + 8) = o1;
}

// ---------------- launcher ---------------------------------------------------
extern "C" void kernel_launch(void* const* d_in, const int* in_sizes, int n_in,
                              void* d_out, int out_size, void* d_ws, size_t ws_size,
                              hipStream_t stream) {
  const float* feat1 = (const float*)d_in[0];
  const float* feat2 = (const float*)d_in[1];
  const float* Wq = (const float*)d_in[2];
  const float* bq = (const float*)d_in[3];
  const float* Wk = (const float*)d_in[4];
  const float* bk = (const float*)d_in[5];
  const float* Wv = (const float*)d_in[6];
  const float* bv = (const float*)d_in[7];
  const float* Wo = (const float*)d_in[8];
  const float* bo = (const float*)d_in[9];
  float* out = (float*)d_out;

  const int M = B_ROWS;
  char* ws = (char*)d_ws;
  const size_t featB = (size_t)M * DIMSZ * 2;   // 32 MB
  const size_t wB = (size_t)DIMSZ * DIMSZ * 2;  // 2 MB
  unsigned short* f1b = (unsigned short*)(ws);
  unsigned short* f2b = (unsigned short*)(ws + featB);
  unsigned short* Qb  = (unsigned short*)(ws + 2 * featB);
  unsigned short* Kb  = (unsigned short*)(ws + 3 * featB);
  unsigned short* Vb  = (unsigned short*)(ws + 4 * featB);
  unsigned short* Wqt = (unsigned short*)(ws + 5 * featB);
  unsigned short* Wkt = (unsigned short*)(ws + 5 * featB + wB);   // Wkt,Wvt adjacent
  unsigned short* Wvt = (unsigned short*)(ws + 5 * featB + 2 * wB);
  unsigned short* Wot = (unsigned short*)(ws + 5 * featB + 3 * wB);
  unsigned short* ctx = f1b;   // f1b dead after Q GEMM

  const int n8 = M * DIMSZ / 8;
  cvt2_k<<<(2 * n8 + 255) / 256, 256, 0, stream>>>(feat1, feat2, f1b, f2b, n8);
  transpose_cvt4_k<<<dim3(32, 32, 4), 256, 0, stream>>>(Wq, Wk, Wv, Wo,
                                                        Wqt, Wkt, Wvt, Wot);

  // Q: N=1024 (256 blocks), KV fused: N=2048 (512 blocks)
  gemm4_k<1024, 1><<<256, 512, 0, stream>>>(f1b, Wqt, bq, bq, Qb, Qb);
  gemm4_k<2048, 1><<<512, 512, 0, stream>>>(f2b, Wkt, bk, bv, Kb, Vb);

  attn_k<<<M / 4, 256, 0, stream>>>(Qb, Kb, Vb, ctx);

  // output projection: fp32 out
  gemm4_k<1024, 0><<<256, 512, 0, stream>>>(ctx, Wot, bo, bo, out, out);
}

// Round 5
// 216.094 us; speedup vs baseline: 1.5071x; 1.0861x over previous
//
#include <hip/hip_runtime.h>
#include <cstdint>
#include <cstddef>

#define B_ROWS 16384
#define DIMSZ  1024
#define NH     8
#define HD     128
#define KDIM   1024

typedef __attribute__((ext_vector_type(8))) __bf16 bf16x8;
typedef __attribute__((ext_vector_type(4))) float f32x4;
typedef __attribute__((ext_vector_type(8))) unsigned short ushort8v;

__device__ __forceinline__ unsigned short f2bf(float f) {
  union { float f; unsigned int u; } x; x.f = f;
  unsigned int r = x.u + 0x7FFFu + ((x.u >> 16) & 1u);   // RNE
  return (unsigned short)(r >> 16);
}
__device__ __forceinline__ float bf2f(unsigned short h) {
  union { unsigned int u; float f; } x; x.u = ((unsigned int)h) << 16;
  return x.f;
}

__device__ __forceinline__ void gload_lds16(const void* g, void* l) {
  __builtin_amdgcn_global_load_lds(
      (__attribute__((address_space(1))) void*)(uintptr_t)g,
      (__attribute__((address_space(3))) void*)(uintptr_t)l, 16, 0, 0);
}

// ---------------- fp32 -> bf16 convert (both features, one launch) -----------
__global__ __launch_bounds__(256) void cvt2_k(const float* __restrict__ a,
                                              const float* __restrict__ b,
                                              unsigned short* __restrict__ oa,
                                              unsigned short* __restrict__ ob,
                                              int n8each) {
  int i = blockIdx.x * 256 + threadIdx.x;
  const float* src; unsigned short* dst; int j;
  if (i < n8each) { src = a; dst = oa; j = i; }
  else            { src = b; dst = ob; j = i - n8each; }
  const float4* p = (const float4*)src + 2 * (size_t)j;
  float4 x = p[0], y = p[1];
  ushort8v o;
  o[0] = f2bf(x.x); o[1] = f2bf(x.y); o[2] = f2bf(x.z); o[3] = f2bf(x.w);
  o[4] = f2bf(y.x); o[5] = f2bf(y.y); o[6] = f2bf(y.z); o[7] = f2bf(y.w);
  *(ushort8v*)(dst + 8 * (size_t)j) = o;
}

// ---------------- all 4 weight transposes, one launch ------------------------
__global__ __launch_bounds__(256) void transpose_cvt4_k(
    const float* __restrict__ W0, const float* __restrict__ W1,
    const float* __restrict__ W2, const float* __restrict__ W3,
    unsigned short* __restrict__ T0, unsigned short* __restrict__ T1,
    unsigned short* __restrict__ T2, unsigned short* __restrict__ T3) {
  const float* W; unsigned short* T;
  switch (blockIdx.z) {
    case 0: W = W0; T = T0; break;
    case 1: W = W1; T = T1; break;
    case 2: W = W2; T = T2; break;
    default: W = W3; T = T3; break;
  }
  __shared__ float tile[32][33];
  int bx = blockIdx.x * 32, by = blockIdx.y * 32;
  int tx = threadIdx.x & 31, ty = threadIdx.x >> 5;
  #pragma unroll
  for (int j = ty; j < 32; j += 8)
    tile[j][tx] = W[(size_t)(by + j) * DIMSZ + bx + tx];
  __syncthreads();
  #pragma unroll
  for (int j = ty; j < 32; j += 8)
    T[(size_t)(bx + j) * DIMSZ + by + tx] = f2bf(tile[tx][j]);
}

// ---------------- bf16 MFMA GEMM, 128x128 tile, 3 blocks/CU ------------------
// C[M,NCOLS] = A[M,K] @ Bt[NCOLS,K]^T + bias.
// BM=BN=128, BK=64, 4 waves (2x2), per-wave 64x64, acc[4][4].
// Single 32 KB LDS buffer, 2 __syncthreads per K-tile (m97 structure);
// stage(t+1) issued BEFORE the 32-MFMA cluster so HBM latency hides under
// compute; cross-block overlap (3 blocks/CU) covers the vmcnt drain at the
// loop-top barrier.  LDS rows are 128 B; reads use the R4-proven 0-conflict
// involution c' = c ^ (row&7) on 16B chunks, staged via inverse-permuted
// global source (rule #21).  T1 XCD swizzle.  Split epilogue for fused KV.
template <int NCOLS, int OUT_BF16>
__global__ __launch_bounds__(256, 3) void gemm5_k(
    const unsigned short* __restrict__ A,
    const unsigned short* __restrict__ Bt,
    const float* __restrict__ bias0, const float* __restrict__ bias1,
    void* __restrict__ out0, void* __restrict__ out1) {
  constexpr int NBC = NCOLS / 128;
  constexpr int NWG = (B_ROWS / 128) * NBC;
  constexpr int NKT = KDIM / 64;   // 16

  __shared__ __align__(16) char Asm[16384];   // A tile 128x64 bf16
  __shared__ __align__(16) char Bsm[16384];   // B tile 128x64 bf16

  const int tid = threadIdx.x;
  const int wid = tid >> 6, lane = tid & 63;
  const int lr = lane & 15, kg = lane >> 4;
  const int wr = wid >> 1, wc = wid & 1;
  const int swz = lr & 7;

  // T1: XCD-aware block swizzle (NWG % 8 == 0 for all instantiations)
  const int x = ((int)blockIdx.x % 8) * (NWG / 8) + (int)blockIdx.x / 8;
  const int bcol = (x % NBC) * 128;
  const int brow = (x / NBC) * 128;

  const char* Ab = (const char*)(A + (size_t)brow * KDIM);
  const char* Bb = (const char*)(Bt + (size_t)bcol * KDIM);

  // staging: 4 rounds x 4KB per operand; dest byte D = j*4096 + tid*16
  // (linear); source applies inverse swizzle: row = D>>7, c = (D>>4)&7,
  // src = row*2048 + ((c ^ (row&7))<<4) + t*128.
  int soff[4];
  #pragma unroll
  for (int j = 0; j < 4; ++j) {
    int D = j * 4096 + tid * 16;
    int row = D >> 7, c = (D >> 4) & 7;
    soff[j] = row * 2048 + ((c ^ (row & 7)) << 4);
  }

  auto stage = [&](int t) {
    #pragma unroll
    for (int j = 0; j < 4; ++j) {
      gload_lds16(Ab + (size_t)soff[j] + t * 128, Asm + j * 4096 + tid * 16);
      gload_lds16(Bb + (size_t)soff[j] + t * 128, Bsm + j * 4096 + tid * 16);
    }
  };

  f32x4 acc[4][4] = {};
  stage(0);

  #pragma unroll 1
  for (int t = 0; t < NKT; ++t) {
    __syncthreads();   // stage(t) landed (drains vmcnt chip-wide)

    bf16x8 af[4][2], bfr[4][2];
    #pragma unroll
    for (int m = 0; m < 4; ++m) {
      int row = wr * 64 + m * 16 + lr;
      #pragma unroll
      for (int kk = 0; kk < 2; ++kk)
        af[m][kk] = *(const bf16x8*)(Asm + row * 128 + (((kk * 4 + kg) ^ swz) << 4));
    }
    #pragma unroll
    for (int n = 0; n < 4; ++n) {
      int row = wc * 64 + n * 16 + lr;
      #pragma unroll
      for (int kk = 0; kk < 2; ++kk)
        bfr[n][kk] = *(const bf16x8*)(Bsm + row * 128 + (((kk * 4 + kg) ^ swz) << 4));
    }
    __syncthreads();   // all waves' reads done -> safe to overwrite

    if (t + 1 < NKT) stage(t + 1);   // latency hides under the MFMAs below

    __builtin_amdgcn_s_setprio(1);
    #pragma unroll
    for (int m = 0; m < 4; ++m)
      #pragma unroll
      for (int n = 0; n < 4; ++n) {
        acc[m][n] = __builtin_amdgcn_mfma_f32_16x16x32_bf16(af[m][0], bfr[n][0], acc[m][n], 0, 0, 0);
        acc[m][n] = __builtin_amdgcn_mfma_f32_16x16x32_bf16(af[m][1], bfr[n][1], acc[m][n], 0, 0, 0);
      }
    __builtin_amdgcn_s_setprio(0);
  }

  // ---- epilogue: split output at col 1024 (for fused KV GEMM) ----
  const float* bias; char* outp; int ocol0;
  if (NCOLS == 1024 || bcol < 1024) { bias = bias0; outp = (char*)out0; ocol0 = bcol; }
  else                              { bias = bias1; outp = (char*)out1; ocol0 = bcol - 1024; }
  const int rq = kg * 4;
  #pragma unroll
  for (int n = 0; n < 4; ++n) {
    int oc = ocol0 + wc * 64 + n * 16 + lr;
    float bb = bias[oc];
    #pragma unroll
    for (int m = 0; m < 4; ++m) {
      int row = brow + wr * 64 + m * 16 + rq;
      #pragma unroll
      for (int r = 0; r < 4; ++r) {
        float v = acc[m][n][r] + bb;
        if (OUT_BF16)
          ((unsigned short*)outp)[(size_t)(row + r) * 1024 + oc] = f2bf(v);
        else
          ((float*)outp)[(size_t)(row + r) * 1024 + oc] = v;
      }
    }
  }
}

// ---------------- per-sample 8x8 cross-head attention ------------------------
__global__ __launch_bounds__(256) void attn_k(const unsigned short* __restrict__ Q,
                                              const unsigned short* __restrict__ Kc,
                                              const unsigned short* __restrict__ V,
                                              unsigned short* __restrict__ ctx) {
  __shared__ __align__(16) unsigned short sm[4][3][NH][136];
  const int wid = threadIdx.x >> 6, lane = threadIdx.x & 63;
  const int b = (blockIdx.x << 2) + wid;

  const unsigned short* bases[3] = { Q + (size_t)b * DIMSZ,
                                     Kc + (size_t)b * DIMSZ,
                                     V + (size_t)b * DIMSZ };
  const int row = lane >> 3, ch = lane & 7;
  #pragma unroll
  for (int m = 0; m < 3; ++m) {
    ushort8v v0 = *(const ushort8v*)(bases[m] + row * HD + ch * 16);
    ushort8v v1 = *(const ushort8v*)(bases[m] + row * HD + ch * 16 + 8);
    *(ushort8v*)&sm[wid][m][row][ch * 16] = v0;
    *(ushort8v*)&sm[wid][m][row][ch * 16 + 8] = v1;
  }
  __syncthreads();

  const int h = lane >> 3, g = lane & 7;
  const unsigned short* qr = &sm[wid][0][h][0];
  const unsigned short* kr = &sm[wid][1][g][0];
  float s = 0.f;
  #pragma unroll
  for (int c = 0; c < 16; ++c) {
    ushort8v qv = *(const ushort8v*)(qr + c * 8);
    ushort8v kv = *(const ushort8v*)(kr + c * 8);
    #pragma unroll
    for (int j = 0; j < 8; ++j) s += bf2f(qv[j]) * bf2f(kv[j]);
  }
  s *= 0.088388347648318447f;

  float mx = s;
  #pragma unroll
  for (int o = 1; o < 8; o <<= 1) mx = fmaxf(mx, __shfl_xor(mx, o));
  float e = __expf(s - mx);
  float sum = e;
  #pragma unroll
  for (int o = 1; o < 8; o <<= 1) sum += __shfl_xor(sum, o);
  float attn = e / sum;

  const int h2 = lane >> 3, d0 = (lane & 7) * 16;
  float cacc[16];
  #pragma unroll
  for (int j = 0; j < 16; ++j) cacc[j] = 0.f;
  #pragma unroll
  for (int g2 = 0; g2 < 8; ++g2) {
    float a = __shfl(attn, (lane & 56) + g2);
    const unsigned short* vr = &sm[wid][2][g2][d0];
    ushort8v v0 = *(const ushort8v*)vr;
    ushort8v v1 = *(const ushort8v*)(vr + 8);
    #pragma unroll
    for (int j = 0; j < 8; ++j) {
      cacc[j]     += a * bf2f(v0[j]);
      cacc[8 + j] += a * bf2f(v1[j]);
    }
  }
  ushort8v o0, o1;
  #pragma unroll
  for (int j = 0; j < 8; ++j) { o0[j] = f2bf(cacc[j]); o1[j] = f2bf(cacc[8 + j]); }
  unsigned short* op = ctx + (size_t)b * DIMSZ + h2 * HD + d0;
  *(ushort8v*)op = o0;
  *(ushort8v*)(op + 8) = o1;
}

// ---------------- launcher ---------------------------------------------------
extern "C" void kernel_launch(void* const* d_in, const int* in_sizes, int n_in,
                              void* d_out, int out_size, void* d_ws, size_t ws_size,
                              hipStream_t stream) {
  const float* feat1 = (const float*)d_in[0];
  const float* feat2 = (const float*)d_in[1];
  const float* Wq = (const float*)d_in[2];
  const float* bq = (const float*)d_in[3];
  const float* Wk = (const float*)d_in[4];
  const float* bk = (const float*)d_in[5];
  const float* Wv = (const float*)d_in[6];
  const float* bv = (const float*)d_in[7];
  const float* Wo = (const float*)d_in[8];
  const float* bo = (const float*)d_in[9];
  float* out = (float*)d_out;

  const int M = B_ROWS;
  char* ws = (char*)d_ws;
  const size_t featB = (size_t)M * DIMSZ * 2;   // 32 MB
  const size_t wB = (size_t)DIMSZ * DIMSZ * 2;  // 2 MB
  unsigned short* f1b = (unsigned short*)(ws);
  unsigned short* f2b = (unsigned short*)(ws + featB);
  unsigned short* Qb  = (unsigned short*)(ws + 2 * featB);
  unsigned short* Kb  = (unsigned short*)(ws + 3 * featB);
  unsigned short* Vb  = (unsigned short*)(ws + 4 * featB);
  unsigned short* Wqt = (unsigned short*)(ws + 5 * featB);
  unsigned short* Wkt = (unsigned short*)(ws + 5 * featB + wB);   // Wkt,Wvt adjacent
  unsigned short* Wvt = (unsigned short*)(ws + 5 * featB + 2 * wB);
  unsigned short* Wot = (unsigned short*)(ws + 5 * featB + 3 * wB);
  unsigned short* ctx = f1b;   // f1b dead after Q GEMM

  const int n8 = M * DIMSZ / 8;
  cvt2_k<<<(2 * n8 + 255) / 256, 256, 0, stream>>>(feat1, feat2, f1b, f2b, n8);
  transpose_cvt4_k<<<dim3(32, 32, 4), 256, 0, stream>>>(Wq, Wk, Wv, Wo,
                                                        Wqt, Wkt, Wvt, Wot);

  // Q: N=1024 (1024 blocks), KV fused: N=2048 (2048 blocks)
  gemm5_k<1024, 1><<<1024, 256, 0, stream>>>(f1b, Wqt, bq, bq, Qb, Qb);
  gemm5_k<2048, 1><<<2048, 256, 0, stream>>>(f2b, Wkt, bk, bv, Kb, Vb);

  attn_k<<<M / 4, 256, 0, stream>>>(Qb, Kb, Vb, ctx);

  // output projection: fp32 out
  gemm5_k<1024, 0><<<1024, 256, 0, stream>>>(ctx, Wot, bo, bo, out, out);
}